// Round 4
// baseline (54901.050 us; speedup 1.0000x reference)
//
#include <hip/hip_runtime.h>

// ---------------------------------------------------------------------------
// R-Net forward on MI355X. fp32, round 4: PERSISTENT weight-stationary attn.
// The attn-LSTM recurrence was per-CU byte-streaming bound (2.2 MB weights
// re-read every one of 256 steps through one CU => ~9.5 ms/dispatch plateau).
// New structure: 16 pairs (batch b, fwd+bwd chains) x 16 slices = 256 WGs;
// each WG holds its 1/16 slice of all weights + attT[b] + Hmem[b] in LDS
// (~150 KB, CDNA4 160KB LDS) for the whole dispatch; per step only ~KBs of
// activations cross L2 with 5 flag syncs (monotonic generations, agent scope).
//   P=256, Q=48, B=16, H=128, D=556, 2H=256, 3H=384, 4H=512
// ---------------------------------------------------------------------------

#define PP 256
#define QQ 48
#define BB 16

__device__ __forceinline__ float fast_rcp(float x) { return __builtin_amdgcn_rcpf(x); }
__device__ __forceinline__ float tanh_f(float x) {
  float e = __expf(2.0f * x);
  return 1.0f - 2.0f * fast_rcp(1.0f + e);
}
__device__ __forceinline__ float sigm_f(float x) {
  return fast_rcp(1.0f + __expf(-x));
}
__device__ __forceinline__ float dot4(float4 a, float4 b) {
  return a.x*b.x + a.y*b.y + a.z*b.z + a.w*b.w;
}

#define FSCOPE __HIP_MEMORY_SCOPE_AGENT
__device__ __forceinline__ void flag_set(int* f, int v) {
  __threadfence();
  __hip_atomic_store(f, v, __ATOMIC_RELAXED, FSCOPE);
}
__device__ __forceinline__ void flag_wait(int* f, int v) {
  int it = 0;
  while (__hip_atomic_load(f, __ATOMIC_RELAXED, FSCOPE) < v) {
    __builtin_amdgcn_s_sleep(2);
    if (++it > 50000) break;   // bounded: a deadlock degrades, never hangs
  }
}

// ---------------------------------------------------------------------------
// Generic C[M,N] = A[M,K] @ W[N,K]^T + bias.  64x64 tiles, BK=16, 256 thr.
// ---------------------------------------------------------------------------
__global__ __launch_bounds__(256) void gemm_nt(
    const float* __restrict__ A, int lda,
    const float* __restrict__ W, int ldw,
    const float* __restrict__ bias,
    float* __restrict__ C, int ldc, int K) {
  __shared__ float As[64][17];
  __shared__ float Ws[64][17];
  int tid = threadIdx.x;
  int m0 = blockIdx.x * 64, n0 = blockIdx.y * 64;
  int lr = tid >> 2, lq = (tid & 3) * 4;
  int tr = tid >> 4, tc = tid & 15;
  float acc[4][4] = {};
  for (int k0 = 0; k0 < K; k0 += 16) {
    float4 av = {0,0,0,0}, wv = {0,0,0,0};
    if (k0 + lq < K) {
      av = *(const float4*)&A[(size_t)(m0 + lr) * lda + k0 + lq];
      wv = *(const float4*)&W[(size_t)(n0 + lr) * ldw + k0 + lq];
    }
    __syncthreads();
    As[lr][lq+0] = av.x; As[lr][lq+1] = av.y; As[lr][lq+2] = av.z; As[lr][lq+3] = av.w;
    Ws[lr][lq+0] = wv.x; Ws[lr][lq+1] = wv.y; Ws[lr][lq+2] = wv.z; Ws[lr][lq+3] = wv.w;
    __syncthreads();
#pragma unroll
    for (int kk = 0; kk < 16; ++kk) {
      float a4[4], b4[4];
#pragma unroll
      for (int i = 0; i < 4; ++i) a4[i] = As[tr*4+i][kk];
#pragma unroll
      for (int j = 0; j < 4; ++j) b4[j] = Ws[tc*4+j][kk];
#pragma unroll
      for (int i = 0; i < 4; ++i)
#pragma unroll
        for (int j = 0; j < 4; ++j) acc[i][j] += a4[i] * b4[j];
    }
  }
#pragma unroll
  for (int i = 0; i < 4; ++i) {
    int m = m0 + tr*4 + i;
#pragma unroll
    for (int j = 0; j < 4; ++j) {
      int n = n0 + tc*4 + j;
      C[(size_t)m * ldc + n] = acc[i][j] + (bias ? bias[n] : 0.0f);
    }
  }
}

// ---------------------------------------------------------------------------
// Batched weight transposes (gru + ptr weights only now)
// ---------------------------------------------------------------------------
struct TDesc { const float* src; float* dst; int R, C, ld, off; };
struct TDescs { TDesc d[16]; };

__global__ __launch_bounds__(256) void transpose_many(TDescs ds) {
  TDesc d = ds.d[blockIdx.y];
  int idx = blockIdx.x * 256 + threadIdx.x;
  if (idx < d.R * d.C) {
    int r = idx / d.C, cc = idx % d.C;
    d.dst[(size_t)cc * d.R + r] = d.src[(size_t)r * d.ld + d.off + cc];
  }
}

// ---------------------------------------------------------------------------
// GRU recurrence. 16 WGs: {p,q} x {fwd,bwd} x 4 b-groups (4 batch each).
// ---------------------------------------------------------------------------
__global__ __launch_bounds__(256) void gru_rec(
    const float* __restrict__ gi_p, const float* __restrict__ gi_q,
    const float* __restrict__ WhhT,  // [128][384] k-major
    const float* __restrict__ bhh,   // [384]
    float* __restrict__ out_p, float* __restrict__ out_q,
    float* __restrict__ Hp, float* __restrict__ Hq,
    int mode0, int finalmode) {
  int x = blockIdx.x;
  int seq = x >> 3, dir = (x >> 2) & 1, bg = x & 3;
  int T = seq ? QQ : PP;
  const float* gi = seq ? gi_q : gi_p;
  float* out = seq ? out_q : out_p;
  float* Hf  = seq ? Hq   : Hp;
  int b0 = bg * 4;
  int tid = threadIdx.x;
  __shared__ float hs[4][128];
  __shared__ float gpart[2][4][384];
  ((float*)hs)[tid] = 0.0f;
  ((float*)hs)[256 + tid] = 0.0f;
  __syncthreads();
  int ks = tid / 96;
  int jq = (tid % 96) * 4;
  for (int t = 0; t < T; ++t) {
    if (tid < 192) {
      float a[4][4] = {};
      const float* wp = WhhT + (size_t)ks*64*384 + jq;
      const int kb = ks*64;
#pragma unroll 8
      for (int k = 0; k < 64; ++k) {
        float4 wv = *(const float4*)&wp[(size_t)k*384];
#pragma unroll
        for (int bb = 0; bb < 4; ++bb) {
          float hv = hs[bb][kb + k];
          a[bb][0] += hv*wv.x; a[bb][1] += hv*wv.y; a[bb][2] += hv*wv.z; a[bb][3] += hv*wv.w;
        }
      }
#pragma unroll
      for (int bb = 0; bb < 4; ++bb) {
        gpart[ks][bb][jq+0]=a[bb][0]; gpart[ks][bb][jq+1]=a[bb][1];
        gpart[ks][bb][jq+2]=a[bb][2]; gpart[ks][bb][jq+3]=a[bb][3];
      }
    }
    __syncthreads();
#pragma unroll
    for (int bb2 = 0; bb2 < 2; ++bb2) {
      int gb = (tid >> 7)*2 + bb2;
      int gj = tid & 127;
      size_t base;
      if (mode0) {
        int girow = dir ? (T-1-t) : t;
        base = ((size_t)girow*BB + b0+gb)*384;
      } else {
        base = (((size_t)dir*T + t)*BB + b0+gb)*384;
      }
      float ghr = bhh[gj]     + gpart[0][gb][gj]     + gpart[1][gb][gj];
      float ghz = bhh[128+gj] + gpart[0][gb][128+gj] + gpart[1][gb][128+gj];
      float ghn = bhh[256+gj] + gpart[0][gb][256+gj] + gpart[1][gb][256+gj];
      float gr = gi[base + gj], gz = gi[base + 128 + gj], gn = gi[base + 256 + gj];
      float r = sigm_f(gr + ghr);
      float z = sigm_f(gz + ghz);
      float n = tanh_f(gn + r * ghn);
      float h2 = (1.0f - z) * n + z * hs[gb][gj];
      hs[gb][gj] = h2;
      if (finalmode) {
        int orow = dir ? (T-1-t) : t;
        Hf[((size_t)orow*BB + b0+gb)*256 + dir*128 + gj] = h2;
      } else {
        out[(((size_t)dir*T + t)*BB + b0+gb)*128 + gj] = h2;
      }
    }
    __syncthreads();
  }
}

// ---------------------------------------------------------------------------
// Persistent weight-stationary gated-attention LSTM.
// Grid 256 = 16 pairs x 16 slices (bid = pair + 16*slice => all slices of a
// pair share an XCD if xcd==bid%8). Block 256. One WG per CU (LDS ~150KB).
// Slice s owns: gate cols [32s,32s+32), hidden cols [8s,8s+8), q rows
// [QN*s, QN*s+QN), handles BOTH chains (fwd rf=t, bwd rb=255-t).
// 5 flag syncs per step, monotonic generations (poison 0xAA.. is negative).
// ---------------------------------------------------------------------------
template<int QN>
__global__ __launch_bounds__(256, 1) void attn_persist(
    const float* __restrict__ Hseq,  // [256,16,256]
    const float* __restrict__ Hmem,  // [16*QN,16,256]
    const float* __restrict__ attM,  // [16*QN,16,128] = Hmem @ Wmem^T
    const float* __restrict__ Xcur,  // [256,16,128]
    const float* __restrict__ Xg,    // [256,16,512] = Hseq @ Wg[:, :256]^T
    const float* __restrict__ watt,  // [128]
    const float* __restrict__ Whid,  // [128][128] raw torch layout [j][k]
    const float* __restrict__ Wg,    // [512][512] raw (cols 256.. used)
    const float* __restrict__ Wih,   // [512][512] raw [j][k]
    const float* __restrict__ Whh,   // [512][128] raw [j][k]
    const float* __restrict__ bias,  // [512]
    float* __restrict__ Hy,          // [256,16,256]
    float* ex, int genbase) {
  const int bid = blockIdx.x;
  const int pair = bid & 15, slice = bid >> 4;
  const int b = pair;
  const int tid = threadIdx.x;

  // LDS: weight/data slices (resident all 256 steps) + working buffers
  __shared__ float4 WihS4[32][129];   // [jl][kq] k-pad row 129
  __shared__ float4 WgwS4[32][65];
  __shared__ float4 WhhS4[32][33];
  __shared__ float4 WhidS4[8][33];
  __shared__ float attS[QN][132];     // [ql][h]
  __shared__ float HmemS[QN][256];    // [ql][d]
  __shared__ float4 hS4[2][32];
  __shared__ float4 wS4[2][64];
  __shared__ float4 zgS4[2][128];
  __shared__ float xhSf[256];
  __shared__ float peS[2][16];
  __shared__ float denS[2];
  __shared__ float uSf[64];
  __shared__ float cS[2][8];
  __shared__ float waS[128];
  __shared__ float red[4][2][32];
  __shared__ float redA[4][2][8];
  float* hSf = (float*)hS4;
  float* wSf = (float*)wS4;
  float* zgSf = (float*)zgS4;

  // exchange region (per pair): floats
  float* exP   = ex + (size_t)pair * 22016;
  float* exXh  = exP;            // [par][ch][128]
  float* exPw  = exP + 512;      // [par][slice][ch][260] (256 pw + denom@256)
  float* exZg  = exP + 17152;    // [par][ch][512]
  float* exGate= exP + 19200;    // [par][ch][512]
  float* exH   = exP + 21248;    // [par][ch][128]
  int*   fl    = (int*)(exP + 21760);  // [5][16]

  // ---- one-time LDS fill ----
  for (int idx = tid; idx < 32*128; idx += 256) {
    int j = idx >> 7, kq = idx & 127;
    WihS4[j][kq] = *(const float4*)&Wih[(size_t)(32*slice + j)*512 + 4*kq];
  }
  for (int idx = tid; idx < 32*64; idx += 256) {
    int j = idx >> 6, kq = idx & 63;
    WgwS4[j][kq] = *(const float4*)&Wg[(size_t)(32*slice + j)*512 + 256 + 4*kq];
  }
  for (int idx = tid; idx < 32*32; idx += 256) {
    int j = idx >> 5, kq = idx & 31;
    WhhS4[j][kq] = *(const float4*)&Whh[(size_t)(32*slice + j)*128 + 4*kq];
  }
  for (int idx = tid; idx < 8*32; idx += 256) {
    int j = idx >> 5, kq = idx & 31;
    WhidS4[j][kq] = *(const float4*)&Whid[(size_t)(8*slice + j)*128 + 4*kq];
  }
  for (int idx = tid; idx < QN*128; idx += 256) {
    int ql = idx >> 7, h2 = idx & 127;
    attS[ql][h2] = attM[((size_t)(QN*slice + ql)*BB + b)*128 + h2];
  }
  for (int idx = tid; idx < QN*256; idx += 256) {
    int ql = idx >> 8, d = idx & 255;
    HmemS[ql][d] = Hmem[((size_t)(QN*slice + ql)*BB + b)*256 + d];
  }
  if (tid < 128) waS[tid] = watt[tid];
  hSf[tid] = 0.0f;
  if (tid < 16) cS[tid >> 3][tid & 7] = 0.0f;
  __syncthreads();

  for (int t = 0; t < PP; ++t) {
    const int rf = t, rb = PP-1-t;
    const int par = t & 1;
    const int gb5 = genbase + t*5;
    // ---- gather h from previous step ----
    if (t > 0) {
      if (tid < 16) flag_wait(&fl[4*16 + tid], genbase + (t-1)*5 + 5);
      __syncthreads(); __threadfence();
      hSf[tid] = exH[((t-1)&1)*256 + tid];
      __syncthreads();
    }
    // ---- Stage A: xh slice = Xcur + h @ Whid^T (own 8 cols) ----
    {
      int j = tid & 7, ks = tid >> 3;         // ks: 32 chunks of 4 k
      float4 wv = WhidS4[j][ks];
      float a0 = dot4(wv, hS4[0][ks]);
      float a1 = dot4(wv, hS4[1][ks]);
      a0 += __shfl_xor(a0, 8);  a1 += __shfl_xor(a1, 8);
      a0 += __shfl_xor(a0, 16); a1 += __shfl_xor(a1, 16);
      a0 += __shfl_xor(a0, 32); a1 += __shfl_xor(a1, 32);
      if (((tid >> 3) & 7) == 0) { redA[tid>>6][0][j] = a0; redA[tid>>6][1][j] = a1; }
    }
    __syncthreads();
    if (tid < 16) {
      int ch = tid >> 3, j = tid & 7;
      int row = ch ? rb : rf;
      float v = redA[0][ch][j] + redA[1][ch][j] + redA[2][ch][j] + redA[3][ch][j]
              + Xcur[((size_t)row*BB + b)*128 + 8*slice + j];
      exXh[par*256 + ch*128 + 8*slice + j] = v;
    }
    __syncthreads();
    if (tid == 0) flag_set(&fl[slice], gb5 + 1);
    if (tid < 16) flag_wait(&fl[tid], gb5 + 1);
    __syncthreads(); __threadfence();
    xhSf[tid] = exXh[par*256 + tid];
    __syncthreads();
    // ---- Stage B: scores for own q rows, both chains ----
    {
      int ql = tid >> 4, ks = tid & 15;       // ks: 16 chunks of 8 h
      if (ql < QN) {
        float sf = 0.0f, sb = 0.0f;
#pragma unroll
        for (int i = 0; i < 8; ++i) {
          int h2 = ks*8 + i;
          float av = attS[ql][h2], wv = waS[h2];
          sf += wv * tanh_f(av + xhSf[h2]);
          sb += wv * tanh_f(av + xhSf[128 + h2]);
        }
        sf += __shfl_xor(sf, 1); sb += __shfl_xor(sb, 1);
        sf += __shfl_xor(sf, 2); sb += __shfl_xor(sb, 2);
        sf += __shfl_xor(sf, 4); sb += __shfl_xor(sb, 4);
        sf += __shfl_xor(sf, 8); sb += __shfl_xor(sb, 8);
        if (ks == 0) { peS[0][ql] = __expf(sf); peS[1][ql] = __expf(sb); }
      }
    }
    __syncthreads();
    // ---- Stage D: pw partials over own q rows ----
    {
      int d = tid;
      float af = 0.0f, ab = 0.0f;
#pragma unroll
      for (int ql = 0; ql < QN; ++ql) {
        float m = HmemS[ql][d];
        af += peS[0][ql] * m; ab += peS[1][ql] * m;
      }
      exPw[par*8320 + slice*520 + d]       = af;
      exPw[par*8320 + slice*520 + 260 + d] = ab;
      if (tid < 2) {
        float dd = 0.0f;
#pragma unroll
        for (int ql = 0; ql < QN; ++ql) dd += peS[tid][ql];
        exPw[par*8320 + slice*520 + tid*260 + 256] = dd;
      }
    }
    __syncthreads();
    if (tid == 0) flag_set(&fl[16 + slice], gb5 + 2);
    if (tid < 16) flag_wait(&fl[16 + tid], gb5 + 2);
    __syncthreads(); __threadfence();
    {  // gather & reduce w (unnormalized) + denom
      int d = tid;
      float f = 0.0f, g = 0.0f;
#pragma unroll
      for (int s = 0; s < 16; ++s) {
        f += exPw[par*8320 + s*520 + d];
        g += exPw[par*8320 + s*520 + 260 + d];
      }
      wSf[d] = f; wSf[256 + d] = g;
      if (tid < 2) {
        float dd = 0.0f;
#pragma unroll
        for (int s = 0; s < 16; ++s) dd += exPw[par*8320 + s*520 + tid*260 + 256];
        denS[tid] = dd;
      }
    }
    __syncthreads();
    // ---- Stage E: u slice = w @ Wgw^T (own 32 cols) ----
    {
      int j = tid & 31, ks = tid >> 5;        // ks: 8 chunks of 8 kq
      float af = 0.0f, ab = 0.0f;
#pragma unroll
      for (int i = 0; i < 8; ++i) {
        int kq = ks*8 + i;
        float4 wv = WgwS4[j][kq];
        af += dot4(wv, wS4[0][kq]);
        ab += dot4(wv, wS4[1][kq]);
      }
      af += __shfl_xor(af, 32); ab += __shfl_xor(ab, 32);
      if ((ks & 1) == 0) { red[tid>>6][0][j] = af; red[tid>>6][1][j] = ab; }
    }
    __syncthreads();
    if (tid < 64) {
      int ch = tid >> 5, j = tid & 31;
      float u = red[0][ch][j] + red[1][ch][j] + red[2][ch][j] + red[3][ch][j];
      uSf[ch*32 + j] = u * fast_rcp(denS[ch]);
    }
    __syncthreads();
    // ---- Stage F: zg slice = z * sigmoid(Xg + u) ----
    if (tid < 64) {
      int ch = tid >> 5, jl = tid & 31;
      int jg = 32*slice + jl;
      int row = ch ? rb : rf;
      float zval = (jg < 256) ? Hseq[((size_t)row*BB + b)*256 + jg]
                              : wSf[ch*256 + (jg - 256)] * fast_rcp(denS[ch]);
      float pre = Xg[((size_t)row*BB + b)*512 + jg] + uSf[ch*32 + jl];
      exZg[par*1024 + ch*512 + jg] = zval * sigm_f(pre);
    }
    __syncthreads();
    if (tid == 0) flag_set(&fl[32 + slice], gb5 + 3);
    if (tid < 16) flag_wait(&fl[32 + tid], gb5 + 3);
    __syncthreads(); __threadfence();
    zgSf[tid]       = exZg[par*1024 + tid];
    zgSf[256 + tid] = exZg[par*1024 + 256 + tid];
    zgSf[512 + tid] = exZg[par*1024 + 512 + tid];
    zgSf[768 + tid] = exZg[par*1024 + 768 + tid];
    __syncthreads();
    // ---- Stage G: gate slice = zg @ Wih^T + h @ Whh^T (own 32 cols) ----
    {
      int j = tid & 31, ks = tid >> 5;        // ks: 8 chunks
      float af = 0.0f, ab = 0.0f;
#pragma unroll
      for (int i = 0; i < 16; ++i) {
        int kq = ks*16 + i;
        float4 wv = WihS4[j][kq];
        af += dot4(wv, zgS4[0][kq]);
        ab += dot4(wv, zgS4[1][kq]);
      }
#pragma unroll
      for (int i = 0; i < 4; ++i) {
        int kq = ks*4 + i;
        float4 wv = WhhS4[j][kq];
        af += dot4(wv, hS4[0][kq]);
        ab += dot4(wv, hS4[1][kq]);
      }
      af += __shfl_xor(af, 32); ab += __shfl_xor(ab, 32);
      if ((ks & 1) == 0) { red[tid>>6][0][j] = af; red[tid>>6][1][j] = ab; }
    }
    __syncthreads();
    if (tid < 64) {
      int ch = tid >> 5, j = tid & 31;
      exGate[par*1024 + ch*512 + 32*slice + j] =
        red[0][ch][j] + red[1][ch][j] + red[2][ch][j] + red[3][ch][j];
    }
    __syncthreads();
    if (tid == 0) flag_set(&fl[48 + slice], gb5 + 4);
    if (tid < 16) flag_wait(&fl[48 + tid], gb5 + 4);
    __syncthreads(); __threadfence();
    // ---- Stage H: LSTM cell for own 8 hidden cols, both chains ----
    if (tid < 16) {
      int ch = tid >> 3, jl = tid & 7;
      int jh = 8*slice + jl;
      int row = ch ? rb : rf;
      const float* gp = exGate + par*1024 + ch*512;
      float gi2 = bias[jh]       + gp[jh];
      float gf2 = bias[128 + jh] + gp[128 + jh];
      float gg2 = bias[256 + jh] + gp[256 + jh];
      float go2 = bias[384 + jh] + gp[384 + jh];
      float ii = sigm_f(gi2), ff2 = sigm_f(gf2), g3 = tanh_f(gg2), oo = sigm_f(go2);
      float cn = ff2 * cS[ch][jl] + ii * g3;
      float hn = oo * tanh_f(cn);
      cS[ch][jl] = cn;
      exH[par*256 + ch*128 + jh] = hn;
      Hy[((size_t)row*BB + b)*256 + ch*128 + jh] = hn;
    }
    __syncthreads();
    if (tid == 0) flag_set(&fl[64 + slice], gb5 + 5);
  }
}

// ---------------------------------------------------------------------------
// Answer pointer network. 16 WGs (one per batch element), 256 threads, 2 steps.
// ---------------------------------------------------------------------------
__global__ __launch_bounds__(256) void ptr_net(
    const float* __restrict__ Hq,    // [48,16,256]
    const float* __restrict__ Hs,    // [256,16,256]
    const float* __restrict__ attp,  // [256,16,128] = Hs@Wal^T
    const float* __restrict__ WaaT,  // [128][128]
    const float* __restrict__ wbeta, // [128]
    const float* __restrict__ WahT,  // [256][128]
    const float* __restrict__ bah,
    const float* __restrict__ WacT,
    const float* __restrict__ bac,
    const float* __restrict__ WihT,  // [256][512]
    const float* __restrict__ WhhT,  // [128][512]
    const float* __restrict__ bptr,  // [512]
    float* __restrict__ out) {       // [2,256,16]
  int b = blockIdx.x;
  int tid = threadIdx.x;
  __shared__ float qp[256], h[128], c[128], haa[128], pe2[256], wv[256], part[1024];
  __shared__ float red[1];
  {
    float acc = 0.0f;
#pragma unroll 8
    for (int q = 0; q < QQ; ++q) acc += Hq[((size_t)q*BB + b)*256 + tid];
    qp[tid] = acc * (1.0f/48.0f);
  }
  __syncthreads();
  if (tid < 128) {
    float ah = bah[tid], ac = bac[tid];
#pragma unroll 8
    for (int k = 0; k < 256; ++k) {
      ah += qp[k] * WahT[k*128 + tid];
      ac += qp[k] * WacT[k*128 + tid];
    }
    h[tid] = ah; c[tid] = ac;
  }
  __syncthreads();
  for (int step = 0; step < 2; ++step) {
    if (tid < 128) {
      float acc = 0.0f;
#pragma unroll 8
      for (int k = 0; k < 128; ++k) acc += h[k] * WaaT[k*128 + tid];
      haa[tid] = acc;
    }
    __syncthreads();
    {
      const float* ap = attp + (size_t)tid*BB*128 + b*128;
      float s = 0.0f;
#pragma unroll 8
      for (int k = 0; k < 128; ++k) s += wbeta[k] * tanh_f(ap[k] + haa[k]);
      pe2[tid] = __expf(s);
    }
    __syncthreads();
    if (tid < 64) {
      float s2 = pe2[tid] + pe2[tid+64] + pe2[tid+128] + pe2[tid+192];
#pragma unroll
      for (int off = 32; off; off >>= 1) s2 += __shfl_down(s2, off);
      if (tid == 0) red[0] = s2;
    }
    __syncthreads();
    float inv = fast_rcp(red[0]);
    out[((size_t)step*PP + tid)*BB + b] = pe2[tid] * inv;
    {
      float acc = 0.0f;
#pragma unroll 8
      for (int p2 = 0; p2 < PP; ++p2) acc += pe2[p2] * Hs[((size_t)p2*BB + b)*256 + tid];
      wv[tid] = acc * inv;
    }
    __syncthreads();
    {
      int jq = tid & 127, kh = tid >> 7;
      float a0=0,a1=0,a2=0,a3=0;
      const float* wp = WihT + (size_t)kh*128*512 + jq*4;
      const float* vp = &wv[kh*128];
#pragma unroll 16
      for (int k = 0; k < 128; ++k) {
        float4 w4 = *(const float4*)&wp[(size_t)k*512];
        float v = vp[k];
        a0 += v*w4.x; a1 += v*w4.y; a2 += v*w4.z; a3 += v*w4.w;
      }
      const float* wp2 = WhhT + (size_t)kh*64*512 + jq*4;
      const float* hp = &h[kh*64];
#pragma unroll
      for (int k = 0; k < 64; ++k) {
        float4 w4 = *(const float4*)&wp2[(size_t)k*512];
        float v = hp[k];
        a0 += v*w4.x; a1 += v*w4.y; a2 += v*w4.z; a3 += v*w4.w;
      }
      part[kh*512 + jq*4 + 0] = a0; part[kh*512 + jq*4 + 1] = a1;
      part[kh*512 + jq*4 + 2] = a2; part[kh*512 + jq*4 + 3] = a3;
    }
    __syncthreads();
    if (tid < 128) {
      float gii = bptr[tid]     + part[tid]     + part[512+tid];
      float gff = bptr[128+tid] + part[128+tid] + part[640+tid];
      float ggg = bptr[256+tid] + part[256+tid] + part[768+tid];
      float goo = bptr[384+tid] + part[384+tid] + part[896+tid];
      float ii = sigm_f(gii), ff = sigm_f(gff), gg = tanh_f(ggg), oo = sigm_f(goo);
      float cn = ff * c[tid] + ii * gg;
      h[tid] = oo * tanh_f(cn); c[tid] = cn;
    }
    __syncthreads();
  }
}

// ---------------------------------------------------------------------------
extern "C" void kernel_launch(void* const* d_in, const int* in_sizes, int n_in,
                              void* d_out, int out_size, void* d_ws, size_t ws_size,
                              hipStream_t stream) {
  const float* p_inp  = (const float*)d_in[0];
  const float* q_inp  = (const float*)d_in[1];
  const float* g0_Wih = (const float*)d_in[2];
  const float* g0_Whh = (const float*)d_in[3];
  const float* g0_bih = (const float*)d_in[4];
  const float* g0_bhh = (const float*)d_in[5];
  const float* g1_Wih = (const float*)d_in[6];
  const float* g1_Whh = (const float*)d_in[7];
  const float* g1_bih = (const float*)d_in[8];
  const float* g1_bhh = (const float*)d_in[9];
  const float* g2_Wih = (const float*)d_in[10];
  const float* g2_Whh = (const float*)d_in[11];
  const float* g2_bih = (const float*)d_in[12];
  const float* g2_bhh = (const float*)d_in[13];
  const float* Wq     = (const float*)d_in[14];
  const float* Wp     = (const float*)d_in[15];
  const float* Wh     = (const float*)d_in[16];
  const float* w_alpha= (const float*)d_in[17];
  const float* Wg_m   = (const float*)d_in[18];
  const float* m_Wih  = (const float*)d_in[19];
  const float* m_Whh  = (const float*)d_in[20];
  const float* m_b    = (const float*)d_in[21];
  const float* Wsp    = (const float*)d_in[22];
  const float* Wsh    = (const float*)d_in[23];
  const float* w_gamma= (const float*)d_in[24];
  const float* Wg_s   = (const float*)d_in[25];
  const float* s_Wih  = (const float*)d_in[26];
  const float* s_Whh  = (const float*)d_in[27];
  const float* s_b    = (const float*)d_in[28];
  const float* Wal    = (const float*)d_in[29];
  const float* Waa    = (const float*)d_in[30];
  const float* w_beta = (const float*)d_in[31];
  const float* Wah    = (const float*)d_in[32];
  const float* bah    = (const float*)d_in[33];
  const float* Wac    = (const float*)d_in[34];
  const float* bac    = (const float*)d_in[35];
  const float* pt_Wih = (const float*)d_in[36];
  const float* pt_Whh = (const float*)d_in[37];
  const float* pt_b   = (const float*)d_in[38];

  float* ws = (float*)d_ws;
  size_t o = 0;
  auto alloc = [&](size_t n) { float* p = ws + o; o += n; return p; };
  float* g0WhhT = alloc(49152);
  float* g1WhhT = alloc(49152);
  float* g2WhhT = alloc(49152);
  float* WaaT   = alloc(16384);
  float* WahT   = alloc(32768);
  float* WacT   = alloc(32768);
  float* ptWihT = alloc(131072);
  float* ptWhhT = alloc(65536);
  float* Hp  = alloc(1048576);   // [256,16,256]
  float* Hq_ = alloc(196608);    // [48,16,256]
  float* Hr  = alloc(1048576);
  float* Hs_ = alloc(1048576);
  float* A   = alloc(6225920);
  // GRU views
  float* gi_p = A;                 // [2,256,16,384] (layer0 uses [256,16,384])
  float* gi_q = A + 3145728;       // [2,48,16,384]
  float* hA_p = A + 3735552;       // [2,256,16,128]
  float* hB_p = A + 4784128;
  float* hA_q = A + 5832704;       // [2,48,16,128]
  float* hB_q = A + 6029312;
  // match views
  float* attq = A;                 // [48,16,128]
  float* Xp   = A + 98304;         // [256,16,128]
  float* XgM  = A + 622592;        // [256,16,512]
  // self views
  float* attsp = A;                // [256,16,128]
  float* XgS   = A + 524288;       // [256,16,512]
  // pointer view
  float* attp = A;                 // [256,16,128]
  // persistent-attn exchange region (dead GRU space at attn time)
  float* EXB = A + 3200000;        // 16 pairs x 22016 floats

  TDescs tds;
  tds.d[0] = { g0_Whh, g0WhhT, 384, 128, 128, 0 };
  tds.d[1] = { g1_Whh, g1WhhT, 384, 128, 128, 0 };
  tds.d[2] = { g2_Whh, g2WhhT, 384, 128, 128, 0 };
  tds.d[3] = { Waa,    WaaT,   128, 128, 128, 0 };
  tds.d[4] = { Wah,    WahT,   128, 256, 256, 0 };
  tds.d[5] = { Wac,    WacT,   128, 256, 256, 0 };
  tds.d[6] = { pt_Wih, ptWihT, 512, 256, 256, 0 };
  tds.d[7] = { pt_Whh, ptWhhT, 512, 128, 128, 0 };
  transpose_many<<<dim3(512, 8), 256, 0, stream>>>(tds);

  // GRU encoder
  gemm_nt<<<dim3(64, 6),  256, 0, stream>>>(p_inp, 556, g0_Wih, 556, g0_bih, gi_p, 384, 556);
  gemm_nt<<<dim3(12, 6),  256, 0, stream>>>(q_inp, 556, g0_Wih, 556, g0_bih, gi_q, 384, 556);
  gru_rec<<<16, 256, 0, stream>>>(gi_p, gi_q, g0WhhT, g0_bhh, hA_p, hA_q, nullptr, nullptr, 1, 0);
  gemm_nt<<<dim3(128, 6), 256, 0, stream>>>(hA_p, 128, g1_Wih, 128, g1_bih, gi_p, 384, 128);
  gemm_nt<<<dim3(24, 6),  256, 0, stream>>>(hA_q, 128, g1_Wih, 128, g1_bih, gi_q, 384, 128);
  gru_rec<<<16, 256, 0, stream>>>(gi_p, gi_q, g1WhhT, g1_bhh, hB_p, hB_q, nullptr, nullptr, 0, 0);
  gemm_nt<<<dim3(128, 6), 256, 0, stream>>>(hB_p, 128, g2_Wih, 128, g2_bih, gi_p, 384, 128);
  gemm_nt<<<dim3(24, 6),  256, 0, stream>>>(hB_q, 128, g2_Wih, 128, g2_bih, gi_q, 384, 128);
  gru_rec<<<16, 256, 0, stream>>>(gi_p, gi_q, g2WhhT, g2_bhh, hA_p, hA_q, Hp, Hq_, 0, 1);

  // match-LSTM (passage attends over question): persistent weight-stationary
  gemm_nt<<<dim3(12, 2), 256, 0, stream>>>(Hq_, 256, Wq, 256, nullptr, attq, 128, 256);
  gemm_nt<<<dim3(64, 2), 256, 0, stream>>>(Hp, 256, Wp, 256, nullptr, Xp, 128, 256);
  gemm_nt<<<dim3(64, 8), 256, 0, stream>>>(Hp, 256, Wg_m, 512, nullptr, XgM, 512, 256);
  attn_persist<3><<<256, 256, 0, stream>>>(Hp, Hq_, attq, Xp, XgM, w_alpha,
                                           Wh, Wg_m, m_Wih, m_Whh, m_b, Hr, EXB, 0);

  // self-matching (Wmem == Wcur == Wsp)
  gemm_nt<<<dim3(64, 2), 256, 0, stream>>>(Hr, 256, Wsp, 256, nullptr, attsp, 128, 256);
  gemm_nt<<<dim3(64, 8), 256, 0, stream>>>(Hr, 256, Wg_s, 512, nullptr, XgS, 512, 256);
  attn_persist<16><<<256, 256, 0, stream>>>(Hr, Hr, attsp, attsp, XgS, w_gamma,
                                            Wsh, Wg_s, s_Wih, s_Whh, s_b, Hs_, EXB, 1280);

  // pointer network
  gemm_nt<<<dim3(64, 2), 256, 0, stream>>>(Hs_, 256, Wal, 256, nullptr, attp, 128, 256);
  ptr_net<<<16, 256, 0, stream>>>(Hq_, Hs_, attp, WaaT, w_beta, WahT, bah, WacT, bac,
                                  ptWihT, ptWhhT, pt_b, (float*)d_out);
}

// Round 5
// 24088.957 us; speedup vs baseline: 2.2791x; 2.2791x over previous
//
#include <hip/hip_runtime.h>

// ---------------------------------------------------------------------------
// R-Net forward on MI355X. Round 5: back to the R2 topology (per-chain WGs,
// LDS-local sync only — R4 proved cross-WG per-step sync costs ~44us/sync),
// attacking the measured per-CU weight-streaming bound (65 GB/s/CU, 2.2MB/step)
// with (a) fp16 weights/memories (half the bytes, fp32 accumulate) and
// (b) 1024-thread attn WGs (16 waves of latency hiding, in-wave shfl reduces).
//   P=256, Q=48, B=16, H=128, D=556, 2H=256, 3H=384, 4H=512
// ---------------------------------------------------------------------------

#define PP 256
#define QQ 48
#define BB 16

typedef _Float16 f16;
typedef f16 f16x4 __attribute__((ext_vector_type(4)));
typedef f16 f16x8 __attribute__((ext_vector_type(8)));

__device__ __forceinline__ float fast_rcp(float x) { return __builtin_amdgcn_rcpf(x); }
__device__ __forceinline__ float tanh_f(float x) {
  float e = __expf(2.0f * x);
  return 1.0f - 2.0f * fast_rcp(1.0f + e);
}
__device__ __forceinline__ float sigm_f(float x) {
  return fast_rcp(1.0f + __expf(-x));
}

// ---------------------------------------------------------------------------
// Generic C[M,N] = A[M,K] @ W[N,K]^T + bias.  64x64 tiles, BK=16, 256 thr.
// ---------------------------------------------------------------------------
__global__ __launch_bounds__(256) void gemm_nt(
    const float* __restrict__ A, int lda,
    const float* __restrict__ W, int ldw,
    const float* __restrict__ bias,
    float* __restrict__ C, int ldc, int K) {
  __shared__ float As[64][17];
  __shared__ float Ws[64][17];
  int tid = threadIdx.x;
  int m0 = blockIdx.x * 64, n0 = blockIdx.y * 64;
  int lr = tid >> 2, lq = (tid & 3) * 4;
  int tr = tid >> 4, tc = tid & 15;
  float acc[4][4] = {};
  for (int k0 = 0; k0 < K; k0 += 16) {
    float4 av = {0,0,0,0}, wv = {0,0,0,0};
    if (k0 + lq < K) {
      av = *(const float4*)&A[(size_t)(m0 + lr) * lda + k0 + lq];
      wv = *(const float4*)&W[(size_t)(n0 + lr) * ldw + k0 + lq];
    }
    __syncthreads();
    As[lr][lq+0] = av.x; As[lr][lq+1] = av.y; As[lr][lq+2] = av.z; As[lr][lq+3] = av.w;
    Ws[lr][lq+0] = wv.x; Ws[lr][lq+1] = wv.y; Ws[lr][lq+2] = wv.z; Ws[lr][lq+3] = wv.w;
    __syncthreads();
#pragma unroll
    for (int kk = 0; kk < 16; ++kk) {
      float a4[4], b4[4];
#pragma unroll
      for (int i = 0; i < 4; ++i) a4[i] = As[tr*4+i][kk];
#pragma unroll
      for (int j = 0; j < 4; ++j) b4[j] = Ws[tc*4+j][kk];
#pragma unroll
      for (int i = 0; i < 4; ++i)
#pragma unroll
        for (int j = 0; j < 4; ++j) acc[i][j] += a4[i] * b4[j];
    }
  }
#pragma unroll
  for (int i = 0; i < 4; ++i) {
    int m = m0 + tr*4 + i;
#pragma unroll
    for (int j = 0; j < 4; ++j) {
      int n = n0 + tc*4 + j;
      C[(size_t)m * ldc + n] = acc[i][j] + (bias ? bias[n] : 0.0f);
    }
  }
}

// ---------------------------------------------------------------------------
// Batched fp32 transposes (pointer-net weights): dst[c*R+r] = src[r*ld+off+c]
// ---------------------------------------------------------------------------
struct TDesc { const float* src; float* dst; int R, C, ld, off; };
struct TDescs { TDesc d[8]; };

__global__ __launch_bounds__(256) void transpose_many(TDescs ds) {
  TDesc d = ds.d[blockIdx.y];
  int idx = blockIdx.x * 256 + threadIdx.x;
  if (idx < d.R * d.C) {
    int r = idx / d.C, cc = idx % d.C;
    d.dst[(size_t)cc * d.R + r] = d.src[(size_t)r * d.ld + d.off + cc];
  }
}

// ---------------------------------------------------------------------------
// Batched fp32->fp16 transposing converts: dst_h[k*R + j] = src[j*ld + off + k]
// (j = src row 0..R-1, k = src col 0..C-1; result is k-major [k][j])
// ---------------------------------------------------------------------------
struct HDesc { const float* src; f16* dst; int R, C, ld, off; };
struct HDescs { HDesc d[11]; };

__global__ __launch_bounds__(256) void conv_w16_many(HDescs ds) {
  HDesc d = ds.d[blockIdx.y];
  int idx = blockIdx.x * 256 + threadIdx.x;
  if (idx < d.R * d.C) {
    int j = idx / d.C, k = idx % d.C;
    d.dst[(size_t)k * d.R + j] = (f16)d.src[(size_t)j * d.ld + d.off + k];
  }
}

// [T,16,D] fp32 -> [16,T,D] fp16  (grid = (T,16), block = D)
__global__ void conv_perm16(const float* __restrict__ src, f16* __restrict__ dst, int D) {
  int t = blockIdx.x, b = blockIdx.y, d = threadIdx.x;
  dst[((size_t)b*gridDim.x + t)*D + d] = (f16)src[((size_t)t*BB + b)*D + d];
}

// ---------------------------------------------------------------------------
// GRU recurrence, fp16 weights. 16 WGs: {p,q} x {fwd,bwd} x 4 b-groups.
// 512 threads: 384 do the h@Whh^T matvec (4-way k-split), 512 do gates (4b x 128).
// ---------------------------------------------------------------------------
__global__ __launch_bounds__(512) void gru_rec(
    const float* __restrict__ gi_p, const float* __restrict__ gi_q,
    const f16* __restrict__ WhhH,   // [128][384] k-major fp16
    const float* __restrict__ bhh,  // [384]
    float* __restrict__ out_p, float* __restrict__ out_q,
    float* __restrict__ Hp, float* __restrict__ Hq,
    int mode0, int finalmode) {
  int x = blockIdx.x;
  int seq = x >> 3, dir = (x >> 2) & 1, bg = x & 3;
  int T = seq ? QQ : PP;
  const float* gi = seq ? gi_q : gi_p;
  float* out = seq ? out_q : out_p;
  float* Hf  = seq ? Hq   : Hp;
  int b0 = bg * 4;
  int tid = threadIdx.x;
  __shared__ float hs[4][128];
  __shared__ float gpart[4][4][384];   // [ksplit][bb][col]
  ((float*)hs)[tid] = 0.0f;
  __syncthreads();
  int ks = tid / 96;            // 0..3 (tid<384)
  int jq = (tid % 96) * 4;      // col quad
  int gb = tid >> 7, gj = tid & 127;   // gate map: 4b x 128
  for (int t = 0; t < T; ++t) {
    if (tid < 384) {
      float a[4][4] = {};
      const f16* wp = WhhH + (size_t)ks*32*384 + jq;
      const int kb = ks*32;
#pragma unroll 8
      for (int k = 0; k < 32; ++k) {
        f16x4 wv = *(const f16x4*)&wp[(size_t)k*384];
        float w0 = (float)wv[0], w1 = (float)wv[1], w2 = (float)wv[2], w3 = (float)wv[3];
#pragma unroll
        for (int bb = 0; bb < 4; ++bb) {
          float hv = hs[bb][kb + k];
          a[bb][0] += hv*w0; a[bb][1] += hv*w1; a[bb][2] += hv*w2; a[bb][3] += hv*w3;
        }
      }
#pragma unroll
      for (int bb = 0; bb < 4; ++bb) {
        gpart[ks][bb][jq+0]=a[bb][0]; gpart[ks][bb][jq+1]=a[bb][1];
        gpart[ks][bb][jq+2]=a[bb][2]; gpart[ks][bb][jq+3]=a[bb][3];
      }
    }
    __syncthreads();
    {
      size_t base;
      if (mode0) {
        int girow = dir ? (T-1-t) : t;
        base = ((size_t)girow*BB + b0+gb)*384;
      } else {
        base = (((size_t)dir*T + t)*BB + b0+gb)*384;
      }
      float ghr = bhh[gj]     + gpart[0][gb][gj]     + gpart[1][gb][gj]     + gpart[2][gb][gj]     + gpart[3][gb][gj];
      float ghz = bhh[128+gj] + gpart[0][gb][128+gj] + gpart[1][gb][128+gj] + gpart[2][gb][128+gj] + gpart[3][gb][128+gj];
      float ghn = bhh[256+gj] + gpart[0][gb][256+gj] + gpart[1][gb][256+gj] + gpart[2][gb][256+gj] + gpart[3][gb][256+gj];
      float gr = gi[base + gj], gz = gi[base + 128 + gj], gn = gi[base + 256 + gj];
      float r = sigm_f(gr + ghr);
      float z = sigm_f(gz + ghz);
      float n = tanh_f(gn + r * ghn);
      float h2 = (1.0f - z) * n + z * hs[gb][gj];
      hs[gb][gj] = h2;
      if (finalmode) {
        int orow = dir ? (T-1-t) : t;
        Hf[((size_t)orow*BB + b0+gb)*256 + dir*128 + gj] = h2;
      } else {
        out[(((size_t)dir*T + t)*BB + b0+gb)*128 + gj] = h2;
      }
    }
    __syncthreads();
  }
}

// ---------------------------------------------------------------------------
// Gated additive-attention LSTM. 32 WGs = {dir} x {b}, 1024 threads.
// fp16 weights (k-major [k][j]) + fp16 attT/Hmem; fp32 state/accumulate.
// In-wave shfl_xor reduces; interleaved k (k = ks + 16*i) keeps LDS broadcast
// reads conflict-free. 8 barriers/step.
// ---------------------------------------------------------------------------
template<int QM>
__global__ __launch_bounds__(1024, 1) void attn_rec(
    const float* __restrict__ Hseq,   // [256,16,256] fp32
    const f16*  __restrict__ HmemH,   // [16][QM][256]
    const f16*  __restrict__ attH,    // [16][QM][128]
    const float* __restrict__ Xcur,   // [256,16,128]
    const float* __restrict__ Xg,     // [256,16,512]
    const float* __restrict__ watt,   // [128]
    const f16*  __restrict__ WhidH,   // [128][128] k-major
    const f16*  __restrict__ WgwH,    // [256][512] k-major
    const f16*  __restrict__ WihH,    // [512][512] k-major
    const f16*  __restrict__ WhhH,    // [128][512] k-major
    const float* __restrict__ bias,   // [512]
    float* __restrict__ Hy) {         // [256,16,256]
  constexpr int QP = (QM == QQ) ? 64 : 256;
  constexpr int RL = QP / 64;
  int dir = blockIdx.x >> 4, b = blockIdx.x & 15;
  int tid = threadIdx.x;
  __shared__ float h[128], cc[128], xh[128], wa[128];
  __shared__ float pe[QP];
  __shared__ float wS[256], uS[512], zgS[512], gS[512];
  __shared__ float pA[8][128];
  __shared__ float denS;
  if (tid < 128) { h[tid] = 0.0f; cc[tid] = 0.0f; wa[tid] = watt[tid]; }
  const f16* attb = attH  + (size_t)b*QM*128;
  const f16* memb = HmemH + (size_t)b*QM*256;
  __syncthreads();
  for (int t = 0; t < PP; ++t) {
    const int row = dir ? (PP-1-t) : t;
    // ---- Stage A: xh = Xcur_row + h @ Whid^T  (8-way k-split, LDS partials)
    {
      int ks = tid >> 7, j = tid & 127;
      float acc = 0.0f;
      const f16* wp = WhidH + (size_t)ks*16*128 + j;
#pragma unroll
      for (int i = 0; i < 16; ++i)
        acc += (float)wp[(size_t)i*128] * h[ks*16 + i];
      pA[ks][j] = acc;
    }
    __syncthreads();
    if (tid < 128) {
      float acc = Xcur[((size_t)row*BB + b)*128 + tid];
#pragma unroll
      for (int i = 0; i < 8; ++i) acc += pA[i][tid];
      xh[tid] = acc;
    }
    __syncthreads();
    // ---- Stage B: scores s[q] = sum_h wa[h] tanh(att[q][h] + xh[h])
    {
      int hs = tid & 15, qq = tid >> 4;     // qq 0..63
#pragma unroll
      for (int r = 0; r < RL; ++r) {
        int q = qq + 64*r;
        float s = 0.0f;
        if (q < QM) {
          f16x8 av = *(const f16x8*)&attb[(size_t)q*128 + hs*8];
#pragma unroll
          for (int i = 0; i < 8; ++i) {
            int h2 = hs*8 + i;
            s += wa[h2] * tanh_f((float)av[i] + xh[h2]);
          }
        }
#pragma unroll
        for (int m = 1; m < 16; m <<= 1) s += __shfl_xor(s, m);
        if (hs == 0) pe[q < QP ? q : 0] = (q < QM) ? __expf(s) : ((q < QP) ? 0.0f : pe[0]);
        if (hs == 0 && q < QP) pe[q] = (q < QM) ? __expf(s) : 0.0f;
      }
    }
    __syncthreads();
    // ---- Stage C: denominator
    if (tid < 64) {
      float s = 0.0f;
#pragma unroll
      for (int i = 0; i < RL; ++i) s += pe[tid + 64*i];
#pragma unroll
      for (int m = 32; m; m >>= 1) s += __shfl_xor(s, m);
      if (tid == 0) denS = s;
    }
    __syncthreads();
    // ---- Stage D: w[d] = sum_q pe[q] * Hmem[q][d]  (32-way q-split, in-wave)
    {
      int doo = tid >> 5, qs = tid & 31;    // doo 0..31 (d-octet), qs 0..31
      float acc[8] = {};
      for (int q = qs; q < QM; q += 32) {
        float pv = pe[q];
        f16x8 mv = *(const f16x8*)&memb[(size_t)q*256 + doo*8];
#pragma unroll
        for (int i = 0; i < 8; ++i) acc[i] += pv * (float)mv[i];
      }
#pragma unroll
      for (int m = 1; m < 32; m <<= 1) {
#pragma unroll
        for (int i = 0; i < 8; ++i) acc[i] += __shfl_xor(acc[i], m);
      }
      if (qs == 0) {
#pragma unroll
        for (int i = 0; i < 8; ++i) wS[doo*8 + i] = acc[i];
      }
    }
    __syncthreads();
    // ---- Stage E: u[j] = (w/den) @ Wgw^T  (16-way k-split, interleaved k)
    {
      int ks = tid & 15, jo = tid >> 4;     // jo 0..63 (j-octet)
      float invd = fast_rcp(denS);
      float acc[8] = {};
#pragma unroll
      for (int i = 0; i < 16; ++i) {
        int k = ks + 16*i;
        float wk = wS[k] * invd;
        f16x8 wv = *(const f16x8*)&WgwH[(size_t)k*512 + jo*8];
#pragma unroll
        for (int c = 0; c < 8; ++c) acc[c] += wk * (float)wv[c];
      }
#pragma unroll
      for (int m = 1; m < 16; m <<= 1) {
#pragma unroll
        for (int c = 0; c < 8; ++c) acc[c] += __shfl_xor(acc[c], m);
      }
      if (ks == 0) {
#pragma unroll
        for (int c = 0; c < 8; ++c) uS[jo*8 + c] = acc[c];
      }
    }
    __syncthreads();
    // ---- Stage F: zg[j] = z[j] * sigmoid(Xg[j] + u[j]), z = [x_t, w/den]
    if (tid < 512) {
      float invd = fast_rcp(denS);
      float zval = (tid < 256) ? Hseq[((size_t)row*BB + b)*256 + tid]
                               : wS[tid - 256] * invd;
      float pre = Xg[((size_t)row*BB + b)*512 + tid] + uS[tid];
      zgS[tid] = zval * sigm_f(pre);
    }
    __syncthreads();
    // ---- Stage G: gates[j] = zg @ Wih^T + h @ Whh^T (16-way k-split)
    {
      int ks = tid & 15, jo = tid >> 4;
      float acc[8] = {};
#pragma unroll 8
      for (int i = 0; i < 32; ++i) {
        int k = ks + 16*i;
        float zk = zgS[k];
        f16x8 wv = *(const f16x8*)&WihH[(size_t)k*512 + jo*8];
#pragma unroll
        for (int c = 0; c < 8; ++c) acc[c] += zk * (float)wv[c];
      }
#pragma unroll
      for (int i = 0; i < 8; ++i) {
        int k = ks + 16*i;
        float hk = h[k];
        f16x8 wv = *(const f16x8*)&WhhH[(size_t)k*512 + jo*8];
#pragma unroll
        for (int c = 0; c < 8; ++c) acc[c] += hk * (float)wv[c];
      }
#pragma unroll
      for (int m = 1; m < 16; m <<= 1) {
#pragma unroll
        for (int c = 0; c < 8; ++c) acc[c] += __shfl_xor(acc[c], m);
      }
      if (ks == 0) {
#pragma unroll
        for (int c = 0; c < 8; ++c) gS[jo*8 + c] = acc[c];
      }
    }
    __syncthreads();
    // ---- Stage H: LSTM cell (gate order i,f,g,o)
    if (tid < 128) {
      float gi2 = bias[tid]       + gS[tid];
      float gf2 = bias[128 + tid] + gS[128 + tid];
      float gg2 = bias[256 + tid] + gS[256 + tid];
      float go2 = bias[384 + tid] + gS[384 + tid];
      float ii = sigm_f(gi2), ff = sigm_f(gf2), gg = tanh_f(gg2), oo = sigm_f(go2);
      float cn = ff * cc[tid] + ii * gg;
      float hn = oo * tanh_f(cn);
      cc[tid] = cn; h[tid] = hn;
      Hy[((size_t)row*BB + b)*256 + dir*128 + tid] = hn;
    }
    __syncthreads();
  }
}

// ---------------------------------------------------------------------------
// Answer pointer network. 16 WGs (one per batch element), 256 threads, 2 steps.
// ---------------------------------------------------------------------------
__global__ __launch_bounds__(256) void ptr_net(
    const float* __restrict__ Hq,    // [48,16,256]
    const float* __restrict__ Hs,    // [256,16,256]
    const float* __restrict__ attp,  // [256,16,128] = Hs@Wal^T
    const float* __restrict__ WaaT,  // [128][128]
    const float* __restrict__ wbeta, // [128]
    const float* __restrict__ WahT,  // [256][128]
    const float* __restrict__ bah,
    const float* __restrict__ WacT,
    const float* __restrict__ bac,
    const float* __restrict__ WihT,  // [256][512]
    const float* __restrict__ WhhT,  // [128][512]
    const float* __restrict__ bptr,  // [512]
    float* __restrict__ out) {       // [2,256,16]
  int b = blockIdx.x;
  int tid = threadIdx.x;
  __shared__ float qp[256], h[128], c[128], haa[128], pe2[256], wv[256], part[1024];
  __shared__ float red[1];
  {
    float acc = 0.0f;
#pragma unroll 8
    for (int q = 0; q < QQ; ++q) acc += Hq[((size_t)q*BB + b)*256 + tid];
    qp[tid] = acc * (1.0f/48.0f);
  }
  __syncthreads();
  if (tid < 128) {
    float ah = bah[tid], ac = bac[tid];
#pragma unroll 8
    for (int k = 0; k < 256; ++k) {
      ah += qp[k] * WahT[k*128 + tid];
      ac += qp[k] * WacT[k*128 + tid];
    }
    h[tid] = ah; c[tid] = ac;
  }
  __syncthreads();
  for (int step = 0; step < 2; ++step) {
    if (tid < 128) {
      float acc = 0.0f;
#pragma unroll 8
      for (int k = 0; k < 128; ++k) acc += h[k] * WaaT[k*128 + tid];
      haa[tid] = acc;
    }
    __syncthreads();
    {
      const float* ap = attp + (size_t)tid*BB*128 + b*128;
      float s = 0.0f;
#pragma unroll 8
      for (int k = 0; k < 128; ++k) s += wbeta[k] * tanh_f(ap[k] + haa[k]);
      pe2[tid] = __expf(s);
    }
    __syncthreads();
    if (tid < 64) {
      float s2 = pe2[tid] + pe2[tid+64] + pe2[tid+128] + pe2[tid+192];
#pragma unroll
      for (int off = 32; off; off >>= 1) s2 += __shfl_down(s2, off);
      if (tid == 0) red[0] = s2;
    }
    __syncthreads();
    float inv = fast_rcp(red[0]);
    out[((size_t)step*PP + tid)*BB + b] = pe2[tid] * inv;
    {
      float acc = 0.0f;
#pragma unroll 8
      for (int p2 = 0; p2 < PP; ++p2) acc += pe2[p2] * Hs[((size_t)p2*BB + b)*256 + tid];
      wv[tid] = acc * inv;
    }
    __syncthreads();
    {
      int jq = tid & 127, kh = tid >> 7;
      float a0=0,a1=0,a2=0,a3=0;
      const float* wp = WihT + (size_t)kh*128*512 + jq*4;
      const float* vp = &wv[kh*128];
#pragma unroll 16
      for (int k = 0; k < 128; ++k) {
        float4 w4 = *(const float4*)&wp[(size_t)k*512];
        float v = vp[k];
        a0 += v*w4.x; a1 += v*w4.y; a2 += v*w4.z; a3 += v*w4.w;
      }
      const float* wp2 = WhhT + (size_t)kh*64*512 + jq*4;
      const float* hp = &h[kh*64];
#pragma unroll
      for (int k = 0; k < 64; ++k) {
        float4 w4 = *(const float4*)&wp2[(size_t)k*512];
        float v = hp[k];
        a0 += v*w4.x; a1 += v*w4.y; a2 += v*w4.z; a3 += v*w4.w;
      }
      part[kh*512 + jq*4 + 0] = a0; part[kh*512 + jq*4 + 1] = a1;
      part[kh*512 + jq*4 + 2] = a2; part[kh*512 + jq*4 + 3] = a3;
    }
    __syncthreads();
    if (tid < 128) {
      float gii = bptr[tid]     + part[tid]     + part[512+tid];
      float gff = bptr[128+tid] + part[128+tid] + part[640+tid];
      float ggg = bptr[256+tid] + part[256+tid] + part[768+tid];
      float goo = bptr[384+tid] + part[384+tid] + part[896+tid];
      float ii = sigm_f(gii), ff = sigm_f(gff), gg = tanh_f(ggg), oo = sigm_f(goo);
      float cn = ff * c[tid] + ii * gg;
      h[tid] = oo * tanh_f(cn); c[tid] = cn;
    }
    __syncthreads();
  }
}

// ---------------------------------------------------------------------------
extern "C" void kernel_launch(void* const* d_in, const int* in_sizes, int n_in,
                              void* d_out, int out_size, void* d_ws, size_t ws_size,
                              hipStream_t stream) {
  const float* p_inp  = (const float*)d_in[0];
  const float* q_inp  = (const float*)d_in[1];
  const float* g0_Wih = (const float*)d_in[2];
  const float* g0_Whh = (const float*)d_in[3];
  const float* g0_bih = (const float*)d_in[4];
  const float* g0_bhh = (const float*)d_in[5];
  const float* g1_Wih = (const float*)d_in[6];
  const float* g1_Whh = (const float*)d_in[7];
  const float* g1_bih = (const float*)d_in[8];
  const float* g1_bhh = (const float*)d_in[9];
  const float* g2_Wih = (const float*)d_in[10];
  const float* g2_Whh = (const float*)d_in[11];
  const float* g2_bih = (const float*)d_in[12];
  const float* g2_bhh = (const float*)d_in[13];
  const float* Wq     = (const float*)d_in[14];
  const float* Wp     = (const float*)d_in[15];
  const float* Wh     = (const float*)d_in[16];
  const float* w_alpha= (const float*)d_in[17];
  const float* Wg_m   = (const float*)d_in[18];
  const float* m_Wih  = (const float*)d_in[19];
  const float* m_Whh  = (const float*)d_in[20];
  const float* m_b    = (const float*)d_in[21];
  const float* Wsp    = (const float*)d_in[22];
  const float* Wsh    = (const float*)d_in[23];
  const float* w_gamma= (const float*)d_in[24];
  const float* Wg_s   = (const float*)d_in[25];
  const float* s_Wih  = (const float*)d_in[26];
  const float* s_Whh  = (const float*)d_in[27];
  const float* s_b    = (const float*)d_in[28];
  const float* Wal    = (const float*)d_in[29];
  const float* Waa    = (const float*)d_in[30];
  const float* w_beta = (const float*)d_in[31];
  const float* Wah    = (const float*)d_in[32];
  const float* bah    = (const float*)d_in[33];
  const float* Wac    = (const float*)d_in[34];
  const float* bac    = (const float*)d_in[35];
  const float* pt_Wih = (const float*)d_in[36];
  const float* pt_Whh = (const float*)d_in[37];
  const float* pt_b   = (const float*)d_in[38];

  float* ws = (float*)d_ws;
  size_t o = 0;
  auto alloc = [&](size_t n) { float* p = ws + o; o += n; return p; };
  // fp32 transposes (pointer net)
  float* WaaT   = alloc(16384);
  float* WahT   = alloc(32768);
  float* WacT   = alloc(32768);
  float* ptWihT = alloc(131072);
  float* ptWhhT = alloc(65536);
  // fp16 weight blocks (sizes in floats = halves/2)
  f16* g0WhhH = (f16*)alloc(24576);
  f16* g1WhhH = (f16*)alloc(24576);
  f16* g2WhhH = (f16*)alloc(24576);
  f16* mWihH  = (f16*)alloc(131072);
  f16* mWgwH  = (f16*)alloc(65536);
  f16* mWhhH  = (f16*)alloc(32768);
  f16* mWhidH = (f16*)alloc(8192);
  f16* sWihH  = (f16*)alloc(131072);
  f16* sWgwH  = (f16*)alloc(65536);
  f16* sWhhH  = (f16*)alloc(32768);
  f16* sWhidH = (f16*)alloc(8192);
  // persistent activations
  float* Hp  = alloc(1048576);   // [256,16,256]
  float* Hq_ = alloc(196608);    // [48,16,256]
  float* Hr  = alloc(1048576);
  float* Hs_ = alloc(1048576);
  // phase-reused region
  float* A = alloc(6225920);
  // GRU views
  float* gi_p = A;                 // [2,256,16,384] (layer0 uses [256,16,384])
  float* gi_q = A + 3145728;       // [2,48,16,384]
  float* hA_p = A + 3735552;       // [2,256,16,128]
  float* hB_p = A + 4784128;
  float* hA_q = A + 5832704;       // [2,48,16,128]
  float* hB_q = A + 6029312;
  // match views
  float* attq  = A;                // [48,16,128] fp32
  float* Xp    = A + 98304;        // [256,16,128]
  float* XgM   = A + 622592;       // [256,16,512]
  f16*   attqH = (f16*)(A + 2719744);  // [16,48,128]
  f16*   HqH   = (f16*)(A + 2768896);  // [16,48,256]
  // self views
  float* attsp  = A;               // [256,16,128]
  float* XgS    = A + 524288;      // [256,16,512]
  f16*   attspH = (f16*)(A + 2621440); // [16,256,128]
  f16*   HrH    = (f16*)(A + 2883584); // [16,256,256]
  // pointer view
  float* attp = A;                 // [256,16,128]

  // 1. fp32 transposes (pointer net weights)
  TDescs tds;
  tds.d[0] = { Waa,    WaaT,   128, 128, 128, 0 };
  tds.d[1] = { Wah,    WahT,   128, 256, 256, 0 };
  tds.d[2] = { Wac,    WacT,   128, 256, 256, 0 };
  tds.d[3] = { pt_Wih, ptWihT, 512, 256, 256, 0 };
  tds.d[4] = { pt_Whh, ptWhhT, 512, 128, 128, 0 };
  tds.d[5] = tds.d[0]; tds.d[6] = tds.d[0]; tds.d[7] = tds.d[0];
  transpose_many<<<dim3(512, 5), 256, 0, stream>>>(tds);

  // 2. fp16 transposing converts (recurrent weights, k-major)
  HDescs hds;
  hds.d[0]  = { g0_Whh, g0WhhH, 384, 128, 128, 0 };
  hds.d[1]  = { g1_Whh, g1WhhH, 384, 128, 128, 0 };
  hds.d[2]  = { g2_Whh, g2WhhH, 384, 128, 128, 0 };
  hds.d[3]  = { m_Wih,  mWihH,  512, 512, 512, 0 };
  hds.d[4]  = { Wg_m,   mWgwH,  512, 256, 512, 256 };
  hds.d[5]  = { m_Whh,  mWhhH,  512, 128, 128, 0 };
  hds.d[6]  = { Wh,     mWhidH, 128, 128, 128, 0 };
  hds.d[7]  = { s_Wih,  sWihH,  512, 512, 512, 0 };
  hds.d[8]  = { Wg_s,   sWgwH,  512, 256, 512, 256 };
  hds.d[9]  = { s_Whh,  sWhhH,  512, 128, 128, 0 };
  hds.d[10] = { Wsh,    sWhidH, 128, 128, 128, 0 };
  conv_w16_many<<<dim3(1024, 11), 256, 0, stream>>>(hds);

  // 3. GRU encoder
  gemm_nt<<<dim3(64, 6),  256, 0, stream>>>(p_inp, 556, g0_Wih, 556, g0_bih, gi_p, 384, 556);
  gemm_nt<<<dim3(12, 6),  256, 0, stream>>>(q_inp, 556, g0_Wih, 556, g0_bih, gi_q, 384, 556);
  gru_rec<<<16, 512, 0, stream>>>(gi_p, gi_q, g0WhhH, g0_bhh, hA_p, hA_q, nullptr, nullptr, 1, 0);
  gemm_nt<<<dim3(128, 6), 256, 0, stream>>>(hA_p, 128, g1_Wih, 128, g1_bih, gi_p, 384, 128);
  gemm_nt<<<dim3(24, 6),  256, 0, stream>>>(hA_q, 128, g1_Wih, 128, g1_bih, gi_q, 384, 128);
  gru_rec<<<16, 512, 0, stream>>>(gi_p, gi_q, g1WhhH, g1_bhh, hB_p, hB_q, nullptr, nullptr, 0, 0);
  gemm_nt<<<dim3(128, 6), 256, 0, stream>>>(hB_p, 128, g2_Wih, 128, g2_bih, gi_p, 384, 128);
  gemm_nt<<<dim3(24, 6),  256, 0, stream>>>(hB_q, 128, g2_Wih, 128, g2_bih, gi_q, 384, 128);
  gru_rec<<<16, 512, 0, stream>>>(gi_p, gi_q, g2WhhH, g2_bhh, hA_p, hA_q, Hp, Hq_, 0, 1);

  // 4. match-LSTM (passage attends over question)
  gemm_nt<<<dim3(12, 2), 256, 0, stream>>>(Hq_, 256, Wq, 256, nullptr, attq, 128, 256);
  gemm_nt<<<dim3(64, 2), 256, 0, stream>>>(Hp, 256, Wp, 256, nullptr, Xp, 128, 256);
  gemm_nt<<<dim3(64, 8), 256, 0, stream>>>(Hp, 256, Wg_m, 512, nullptr, XgM, 512, 256);
  conv_perm16<<<dim3(48, 16), 128, 0, stream>>>(attq, attqH, 128);
  conv_perm16<<<dim3(48, 16), 256, 0, stream>>>(Hq_, HqH, 256);
  attn_rec<QQ><<<32, 1024, 0, stream>>>(Hp, HqH, attqH, Xp, XgM, w_alpha,
                                        mWhidH, mWgwH, mWihH, mWhhH, m_b, Hr);

  // 5. self-matching (Wmem == Wcur == Wsp: one projection serves both)
  gemm_nt<<<dim3(64, 2), 256, 0, stream>>>(Hr, 256, Wsp, 256, nullptr, attsp, 128, 256);
  gemm_nt<<<dim3(64, 8), 256, 0, stream>>>(Hr, 256, Wg_s, 512, nullptr, XgS, 512, 256);
  conv_perm16<<<dim3(256, 16), 128, 0, stream>>>(attsp, attspH, 128);
  conv_perm16<<<dim3(256, 16), 256, 0, stream>>>(Hr, HrH, 256);
  attn_rec<PP><<<32, 1024, 0, stream>>>(Hr, HrH, attspH, attsp, XgS, w_gamma,
                                        sWhidH, sWgwH, sWihH, sWhhH, s_b, Hs_);

  // 6. pointer network
  gemm_nt<<<dim3(64, 2), 256, 0, stream>>>(Hs_, 256, Wal, 256, nullptr, attp, 128, 256);
  ptr_net<<<16, 256, 0, stream>>>(Hq_, Hs_, attp, WaaT, w_beta, WahT, bah, WacT, bac,
                                  ptWihT, ptWhhT, pt_b, (float*)d_out);
}